// Round 4
// baseline (57.082 us; speedup 1.0000x reference)
//
#include <hip/hip_runtime.h>
#include <hip/hip_bf16.h>

// FeatureContrast: out[b,i,j,hw] = x[b,c,hw]*exp(w*x[b,c,hw]) / sum_{3x3 ch window}
// over the 16x16 channel grid, c=(i+1)*16+(j+1). B=32, HW=4096.
//
// R4 = R3 with clang ext_vector float4 (HIP_vector_type rejected by
// __builtin_nontemporal_store). One thread = 4 hw pixels, one output row i.
// Wave-level access per channel row: 1KB contiguous; nontemporal stores keep
// the input L3-resident.

#define NIN 16
#define NOUT 14
#define HW 4096

typedef float f4 __attribute__((ext_vector_type(4)));

__global__ __launch_bounds__(256) void fc_kernel(
    const float* __restrict__ x,
    const float* __restrict__ wp,
    float* __restrict__ out)
{
    const float w = wp[0];
    const int hw4 = (blockIdx.x * blockDim.x + threadIdx.x) * 4;  // 0..4092
    const int i   = blockIdx.y;                                   // 0..13
    const int b   = blockIdx.z;                                   // 0..31

    const float* xb = x + ((size_t)(b * (NIN * NIN) + i * NIN)) * HW + hw4;

    f4 cs[NIN];    // column sums of exp over the 3 channel rows
    f4 num[NIN];   // x*exp(w*x) of middle row (only c=1..14 used)

    // Row i
    #pragma unroll
    for (int c = 0; c < NIN; ++c) {
        f4 v = *(const f4*)(xb + (size_t)c * HW);
        f4 e;
        e.x = __expf(v.x * w);
        e.y = __expf(v.y * w);
        e.z = __expf(v.z * w);
        e.w = __expf(v.w * w);
        cs[c] = e;
    }
    // Row i+1 (middle: numerator source)
    #pragma unroll
    for (int c = 0; c < NIN; ++c) {
        f4 v = *(const f4*)(xb + (size_t)(NIN + c) * HW);
        f4 e;
        e.x = __expf(v.x * w);
        e.y = __expf(v.y * w);
        e.z = __expf(v.z * w);
        e.w = __expf(v.w * w);
        cs[c] += e;
        if (c >= 1 && c <= NOUT) {   // compile-time folded per unrolled iter
            num[c] = v * e;
        }
    }
    // Row i+2
    #pragma unroll
    for (int c = 0; c < NIN; ++c) {
        f4 v = *(const f4*)(xb + (size_t)(2 * NIN + c) * HW);
        f4 e;
        e.x = __expf(v.x * w);
        e.y = __expf(v.y * w);
        e.z = __expf(v.z * w);
        e.w = __expf(v.w * w);
        cs[c] += e;
    }

    float* ob = out + ((size_t)(b * (NOUT * NOUT) + i * NOUT)) * HW + hw4;
    #pragma unroll
    for (int j = 0; j < NOUT; ++j) {
        f4 s = cs[j] + cs[j + 1] + cs[j + 2];
        f4 d;
        d.x = __fdividef(num[j + 1].x, s.x);
        d.y = __fdividef(num[j + 1].y, s.y);
        d.z = __fdividef(num[j + 1].z, s.z);
        d.w = __fdividef(num[j + 1].w, s.w);
        __builtin_nontemporal_store(d, (f4*)(ob + (size_t)j * HW));
    }
}

extern "C" void kernel_launch(void* const* d_in, const int* in_sizes, int n_in,
                              void* d_out, int out_size, void* d_ws, size_t ws_size,
                              hipStream_t stream) {
    const float* x  = (const float*)d_in[0];
    const float* wp = (const float*)d_in[1];
    float* out = (float*)d_out;

    dim3 block(256, 1, 1);
    dim3 grid(HW / (256 * 4), NOUT, 32);   // 4 x 14 x 32 = 1792 blocks (7/CU)
    hipLaunchKernelGGL(fc_kernel, grid, block, 0, stream, x, wp, out);
}

// Round 5
// 51.494 us; speedup vs baseline: 1.1085x; 1.1085x over previous
//
#include <hip/hip_runtime.h>
#include <hip/hip_bf16.h>

// FeatureContrast: out[b,i,j,hw] = x[b,c,hw]*exp(w*x[b,c,hw]) / sum_{3x3 ch window}
// over 16x16 channel grid, c=(i+1)*16+(j+1). B=32, HW=4096.
//
// R5: float2/thread, one thread = one output row i. Loads of each channel row
// issued as an explicit 16-wide batch (separate loop) so they go out
// back-to-back (R4's VGPR=56 showed the compiler serialized f4 state into
// 2-3 outstanding loads -> latency-bound at 2.7 TB/s). Plain stores (nt
// correlated with FETCH doubling 65->128MB). Grid 3584 blocks.

#define NIN 16
#define NOUT 14
#define HW 4096

typedef float f2 __attribute__((ext_vector_type(2)));

__global__ __launch_bounds__(256) void fc_kernel(
    const float* __restrict__ x,
    const float* __restrict__ wp,
    float* __restrict__ out)
{
    const float w = wp[0];
    const int hw2 = (blockIdx.x * blockDim.x + threadIdx.x) * 2;  // 0..4094
    const int i   = blockIdx.y;                                   // 0..13
    const int b   = blockIdx.z;                                   // 0..31

    const float* xb = x + ((size_t)(b * (NIN * NIN) + i * NIN)) * HW + hw2;

    f2 cs[NIN];        // column sums of exp over the 3 channel rows
    f2 num[NIN];       // x*exp(w*x) of middle row (c=1..14 used)
    f2 v[NIN];         // load batch (all 16 loads issued before any exp)

    // ---- Row i ----
    #pragma unroll
    for (int c = 0; c < NIN; ++c) v[c] = *(const f2*)(xb + (size_t)c * HW);
    #pragma unroll
    for (int c = 0; c < NIN; ++c) {
        f2 e; e.x = __expf(v[c].x * w); e.y = __expf(v[c].y * w);
        cs[c] = e;
    }
    // ---- Row i+1 (middle: numerator source) ----
    #pragma unroll
    for (int c = 0; c < NIN; ++c) v[c] = *(const f2*)(xb + (size_t)(NIN + c) * HW);
    #pragma unroll
    for (int c = 0; c < NIN; ++c) {
        f2 e; e.x = __expf(v[c].x * w); e.y = __expf(v[c].y * w);
        cs[c] += e;
        num[c] = v[c] * e;
    }
    // ---- Row i+2 ----
    #pragma unroll
    for (int c = 0; c < NIN; ++c) v[c] = *(const f2*)(xb + (size_t)(2 * NIN + c) * HW);
    #pragma unroll
    for (int c = 0; c < NIN; ++c) {
        f2 e; e.x = __expf(v[c].x * w); e.y = __expf(v[c].y * w);
        cs[c] += e;
    }

    // ---- Output row i ----
    float* ob = out + ((size_t)(b * (NOUT * NOUT) + i * NOUT)) * HW + hw2;
    #pragma unroll
    for (int j = 0; j < NOUT; ++j) {
        f2 s = cs[j] + cs[j + 1] + cs[j + 2];
        f2 d;
        d.x = __fdividef(num[j + 1].x, s.x);
        d.y = __fdividef(num[j + 1].y, s.y);
        *(f2*)(ob + (size_t)j * HW) = d;
    }
}

extern "C" void kernel_launch(void* const* d_in, const int* in_sizes, int n_in,
                              void* d_out, int out_size, void* d_ws, size_t ws_size,
                              hipStream_t stream) {
    const float* x  = (const float*)d_in[0];
    const float* wp = (const float*)d_in[1];
    float* out = (float*)d_out;

    dim3 block(256, 1, 1);
    dim3 grid(HW / (256 * 2), NOUT, 32);   // 8 x 14 x 32 = 3584 blocks (14/CU)
    hipLaunchKernelGGL(fc_kernel, grid, block, 0, stream, x, wp, out);
}